// Round 1
// baseline (99.028 us; speedup 1.0000x reference)
//
#include <hip/hip_runtime.h>

// Grouped conv1d over W + roll(+1) along H.
// x: (128, 48, 28, 28) f32, channel = g*24+ci (group-major)
// w: (24, 96, 7) f32, w[ci][o][k], shared across the 2 groups
// out: (128, 192, 28, 28) f32, channel = g*96+o
// out[b][g*96+o][h][t] = sum_{ci,k} x[b][g*24+ci][(h-1)%28][t+k-3] * w[ci][o][k]

#define BB   128
#define HH   28
#define WWID 28
#define GG   2
#define CINN 24
#define COUTT 96
#define KK   7
#define CTOT 192   // GG*COUTT

__global__ __launch_bounds__(192)
void conv_roll_kernel(const float* __restrict__ x,
                      const float* __restrict__ w,
                      float* __restrict__ out) {
    const int bh = blockIdx.x;      // 0 .. 128*28-1
    const int b  = bh / HH;
    const int h  = bh % HH;         // h_src (pre-roll)
    const int tid = threadIdx.x;    // 0..191

    // Padded input rows: xs[ch][p], p=0..35, value at wsrc = p-3 (zeros outside).
    __shared__ __align__(16) float xs[48][36];
    for (int i = tid; i < 48 * 36; i += 192) {
        const int ch = i / 36;
        const int p  = i % 36;
        const int ws = p - 3;
        float v = 0.0f;
        if (ws >= 0 && ws < WWID)
            v = x[((size_t)(b * 48 + ch) * HH + h) * WWID + ws];
        xs[ch][p] = v;
    }
    __syncthreads();

    const int c = tid;              // output channel 0..191
    const int g = c / COUTT;        // group
    const int o = c - g * COUTT;    // cout within group

    float acc[WWID];
#pragma unroll
    for (int i = 0; i < WWID; ++i) acc[i] = 0.0f;

    const float* wbase = w + (size_t)o * KK;          // + ci*(COUTT*KK)
    const float* xrow0 = &xs[g * CINN][0];

    for (int ci = 0; ci < CINN; ++ci) {
        // 7 weights for (ci, o) — contiguous, L1/L2-resident
        float wk[KK];
        const float* wp = wbase + (size_t)ci * (COUTT * KK);
#pragma unroll
        for (int k = 0; k < KK; ++k) wk[k] = wp[k];

        // padded x row into registers (broadcast LDS reads, conflict-free)
        const float* xr = xrow0 + ci * 36;
        float xv[34];
#pragma unroll
        for (int i = 0; i < 34; ++i) xv[i] = xr[i];

        // 196 FMAs, all register-resident
#pragma unroll
        for (int k = 0; k < KK; ++k)
#pragma unroll
            for (int t = 0; t < WWID; ++t)
                acc[t] += xv[t + k] * wk[k];
    }

    // Transpose through LDS so the global store is fully coalesced
    // (direct per-thread stores would be 16B scatters at 3136B stride).
    __shared__ __align__(16) float ys[CTOT][WWID];
#pragma unroll
    for (int i = 0; i < WWID; ++i) ys[c][i] = acc[i];
    __syncthreads();

    int hd = h + 1; if (hd == HH) hd = 0;   // roll(+1) along H

    const float4* ysv = (const float4*)&ys[0][0];
    for (int i = tid; i < (CTOT * WWID) / 4; i += 192) {
        const float4 v = ysv[i];
        const int e  = i * 4;
        const int cc = e / WWID;
        const int ww = e - cc * WWID;
        float* op = out + (((size_t)(b * CTOT + cc) * HH) + hd) * WWID + ww;
        *(float4*)op = v;
    }
}

extern "C" void kernel_launch(void* const* d_in, const int* in_sizes, int n_in,
                              void* d_out, int out_size, void* d_ws, size_t ws_size,
                              hipStream_t stream) {
    const float* x = (const float*)d_in[0];
    const float* w = (const float*)d_in[1];
    float* out = (float*)d_out;
    dim3 grid(BB * HH);   // 3584 blocks, one per (b, h_src)
    conv_roll_kernel<<<grid, 192, 0, stream>>>(x, w, out);
}

// Round 2
// 42.109 us; speedup vs baseline: 2.3517x; 2.3517x over previous
//
#include <hip/hip_runtime.h>

// Grouped conv1d over W + roll(+1) along H, via bf16 MFMA.
// x: (128, 48, 28, 28) f32, channel = g*24+ci
// w: (24, 96, 7) f32, w[ci][o][k], shared across the 2 groups
// out: (128, 192, 28, 28) f32, channel = g*96+o
// GEMM view per (b, hquad, g): M=112 (4 h-rows x 28 W), N=96, K=168 (pad 192)
// A[m][kk] = x[g*24+kk/7][h0+m/28][(m%28)+(kk%7)-3]; B[kk][o] = w[kk/7][o][kk%7]

typedef __attribute__((ext_vector_type(8))) short short8;
typedef __attribute__((ext_vector_type(4))) float float4v;

#define B_     128
#define H_     28
#define W_     28
#define CIN_   24
#define COUT_  96
#define K_     7
#define KTOT   168
#define KSTEPS 6      // K padded to 192 = 6 x 32
#define NT_    6      // 96 / 16 N-tiles
#define MT_    7      // 112 / 16 M-tiles (one per wave)
#define HQROWS 4      // h-rows per block; 28 = 7 quads

// float -> bf16 bits, round-to-nearest-even
static __device__ __forceinline__ short f2bf(float f) {
    union { float f; unsigned u; } v; v.f = f;
    unsigned r = v.u + 0x7fffu + ((v.u >> 16) & 1u);
    return (short)(r >> 16);
}

// Pre-pack shared weights into MFMA B-fragment order: wf[ks][nt][lane] = bf16x8
// B-frag layout (16x16x32): lane l holds B[(l>>4)*8 + j][nt*16 + (l&15)], j=0..7
__global__ __launch_bounds__(64)
void wfrag_kernel(const float* __restrict__ w, short8* __restrict__ wf) {
    const int idx  = blockIdx.x;          // 0..35 = ks*6 + nt
    const int ks   = idx / 6, nt = idx - ks * 6;
    const int lane = threadIdx.x;
    const int c    = nt * 16 + (lane & 15);
    const int kk0  = ks * 32 + (lane >> 4) * 8;
    short8 v;
#pragma unroll
    for (int j = 0; j < 8; ++j) {
        const int kk = kk0 + j;
        float val = 0.0f;
        if (kk < KTOT) {
            const int ci = kk / 7, k = kk - ci * 7;
            val = w[ci * (COUT_ * K_) + c * K_ + k];
        }
        v[j] = f2bf(val);
    }
    wf[idx * 64 + lane] = v;
}

__global__ __launch_bounds__(448)
void conv_mfma_kernel(const float* __restrict__ x,
                      const short8* __restrict__ wf,
                      float* __restrict__ out) {
    const int bid = blockIdx.x;           // 128 * 7 * 2 = 1792
    const int g   = bid & 1;
    const int hq  = (bid >> 1) % 7;
    const int b   = bid / 14;
    const int h0  = hq * HQROWS;
    const int tid = threadIdx.x;

    // Padded x rows for this (b, hquad, group): value at p is x[.., p-3], zeros outside.
    __shared__ float xs[CIN_][HQROWS][36];   // 13.8 KB
    for (int i = tid; i < CIN_ * HQROWS * 36; i += 448) {
        const int ch  = i / (HQROWS * 36);
        const int rem = i - ch * (HQROWS * 36);
        const int hl  = rem / 36;
        const int p   = rem - hl * 36;
        const int wsrc = p - 3;
        float v = 0.0f;
        if (wsrc >= 0 && wsrc < W_)
            v = x[((size_t)(b * 48 + g * CIN_ + ch) * H_ + (h0 + hl)) * W_ + wsrc];
        xs[ch][hl][p] = v;
    }
    __syncthreads();

    const int wv   = tid >> 6;            // 0..6 : M-tile
    const int lane = tid & 63;
    const int cgrp = lane & 15;
    const int kgrp = lane >> 4;

    // A-frag row for this lane (row = lane&15 within M-tile)
    const int mA = wv * 16 + (lane & 15); // 0..111
    const int hA = mA / 28;
    const int tA = mA - hA * 28;

    float4v acc[NT_];
#pragma unroll
    for (int i = 0; i < NT_; ++i) acc[i] = (float4v)(0.0f);

#pragma unroll
    for (int ks = 0; ks < KSTEPS; ++ks) {
        // B fragments: L2-hot dwordx4 loads, identical across blocks
        short8 br[NT_];
#pragma unroll
        for (int nt = 0; nt < NT_; ++nt)
            br[nt] = wf[(ks * NT_ + nt) * 64 + lane];

        // A fragment via im2col from LDS: k = (lane>>4)*8 + j within this k-step
        short8 a;
#pragma unroll
        for (int j = 0; j < 8; ++j) {
            const int kk = ks * 32 + kgrp * 8 + j;
            float v = 0.0f;
            if (kk < KTOT) {
                const int ci = kk / 7;
                const int k  = kk - ci * 7;
                v = xs[ci][hA][tA + k];
            }
            a[j] = f2bf(v);
        }

#pragma unroll
        for (int nt = 0; nt < NT_; ++nt)
            acc[nt] = __builtin_amdgcn_mfma_f32_16x16x32_bf16(a, br[nt], acc[nt], 0, 0, 0);
    }

    // D layout: row = (lane>>4)*4 + j, col = lane&15. Scatter dword stores;
    // each block covers contiguous 448B per channel -> L2 coalesces.
    const int cbase = g * COUT_;
#pragma unroll
    for (int nt = 0; nt < NT_; ++nt) {
        const int c_out = cbase + nt * 16 + cgrp;
#pragma unroll
        for (int j = 0; j < 4; ++j) {
            const int m  = wv * 16 + kgrp * 4 + j;   // 0..111
            const int hl = m / 28;
            const int t  = m - hl * 28;
            int hd = h0 + hl + 1; if (hd >= H_) hd -= H_;   // roll(+1)
            out[((size_t)(b * 192 + c_out) * H_ + hd) * W_ + t] = acc[nt][j];
        }
    }
}

extern "C" void kernel_launch(void* const* d_in, const int* in_sizes, int n_in,
                              void* d_out, int out_size, void* d_ws, size_t ws_size,
                              hipStream_t stream) {
    const float* x = (const float*)d_in[0];
    const float* w = (const float*)d_in[1];
    float* out = (float*)d_out;
    short8* wf = (short8*)d_ws;           // 36 frags * 64 lanes * 16B = 36864 B

    wfrag_kernel<<<36, 64, 0, stream>>>(w, wf);
    conv_mfma_kernel<<<B_ * 7 * 2, 448, 0, stream>>>(x, wf, out);
}

// Round 3
// 34.160 us; speedup vs baseline: 2.8990x; 1.2327x over previous
//
#include <hip/hip_runtime.h>

// Grouped conv1d over W + roll(+1) along H, bf16 MFMA, LDS-resident operands.
// x: (128, 48, 28, 28) f32, channel = g*24+ci
// w: (24, 96, 7) f32, w[ci][o][k], shared across the 2 groups
// out: (128, 192, 28, 28) f32, channel = g*96+o
//
// GEMM per (b, hquad, g): M=112 (4 h-rows x 28 W), N=96, K=168 pad 192.
// k-axis PERMUTATION (must match between A and B):
//   hw slot = ks*32 + kgrp*8 + j, q = ks*4+kgrp (0..23)
//   q<21: k = q/3, ci = (q%3)*8 + j ; q>=21: zero (enforced on B side only)

typedef __attribute__((ext_vector_type(8))) short short8;
typedef __attribute__((ext_vector_type(4))) float float4v;

#define B_     128
#define H_     28
#define W_     28
#define CIN_   24
#define COUT_  96
#define K_     7
#define KSTEPS 6
#define NT_    6
#define YSLD   114        // ys leading-dim pad (even -> float2-aligned, spreads banks)

// float -> bf16 bits, RNE
static __device__ __forceinline__ unsigned f2bf_u(float f) {
    union { float f; unsigned u; } v; v.f = f;
    return (v.u + 0x7fffu + ((v.u >> 16) & 1u)) >> 16;
}
static __device__ __forceinline__ short f2bf(float f) { return (short)f2bf_u(f); }

// Pre-pack weights into B-fragment order with the permuted k-axis.
// B-frag (16x16x32): lane l holds B[hw=(l>>4)*8+j][col=l&15], j=0..7
__global__ __launch_bounds__(64)
void wfrag_kernel(const float* __restrict__ w, short8* __restrict__ wf) {
    const int idx  = blockIdx.x;          // 0..35 = ks*6 + nt
    const int ks   = idx / 6, nt = idx - ks * 6;
    const int lane = threadIdx.x;
    const int c    = nt * 16 + (lane & 15);
    const int q    = ks * 4 + (lane >> 4);
    short8 v;
    if (q < 21) {
        const int k   = (q * 11) >> 5;    // q/3 for q in 0..23
        const int ci0 = (q - 3 * k) * 8;
#pragma unroll
        for (int j = 0; j < 8; ++j)
            v[j] = f2bf(w[(ci0 + j) * (COUT_ * K_) + c * K_ + k]);
    } else {
#pragma unroll
        for (int j = 0; j < 8; ++j) v[j] = 0;   // zero-pad: makes A garbage harmless
    }
    wf[idx * 64 + lane] = v;
}

__global__ __launch_bounds__(448)
void conv_mfma_kernel(const float* __restrict__ x,
                      const float4* __restrict__ wfg,
                      float* __restrict__ out) {
    const int bid = blockIdx.x;           // 128*7*2 = 1792
    const int g   = bid & 1;
    const int hq  = (bid >> 1) % 7;
    const int b   = bid / 14;
    const int h0  = hq * 4;
    const int tid = threadIdx.x;

    // LDS: xs [4][36][24] bf16 (6912B) | wf 2304*short8 (36864B, aliased by ys after K loop)
    __shared__ __align__(16) char smem[6912 + 36864];
    short*  xs  = (short*)smem;
    short8* wfl = (short8*)(smem + 6912);
    float*  ys0 = (float*)(smem + 6912);            // [16][YSLD]
    float*  ys1 = (float*)(smem + 6912 + 16 * YSLD * 4);

    // Stage W fragments global -> LDS (contiguous float4, conflict-free)
    {
        float4* wdst = (float4*)(smem + 6912);
        for (int i = tid; i < 2304; i += 448) wdst[i] = wfg[i];
    }

    // Stage x as bf16 pairs into xs[hl][p][ci] (p = t+3 padded coord)
    // iter order: p fastest -> coalesced global reads
    for (int idx = tid; idx < 4 * 12 * 36; idx += 448) {
        const int p  = idx % 36;
        const int t2 = idx / 36;
        const int cp = t2 % 12;           // ci pair
        const int hl = t2 / 12;
        const int ws = p - 3;
        float v0 = 0.0f, v1 = 0.0f;
        if (ws >= 0 && ws < W_) {
            const size_t base = ((size_t)(b * 48 + g * CIN_ + cp * 2) * H_ + (h0 + hl)) * W_ + ws;
            v0 = x[base];
            v1 = x[base + (size_t)H_ * W_];
        }
        ((unsigned*)xs)[(hl * 36 + p) * 12 + cp] = f2bf_u(v0) | (f2bf_u(v1) << 16);
    }
    __syncthreads();

    const int lane = tid & 63;
    const int wv   = tid >> 6;            // 0..6 : M-tile
    const int cgrp = lane & 15;
    const int kgrp = lane >> 4;

    // A-frag row for this lane
    const int mA = wv * 16 + cgrp;        // 0..111
    const int hA = mA / 28;
    const int tA = mA - hA * 28;

    // Per-ks A short-index (8 contiguous bf16 -> one ds_read_b128)
    int sidx[KSTEPS];
#pragma unroll
    for (int ks = 0; ks < KSTEPS; ++ks) {
        const int q   = ks * 4 + kgrp;
        const int k   = (q * 11) >> 5;
        const int ci0 = (q - 3 * k) * 8;
        sidx[ks] = (hA * 36 + tA + k) * 24 + ci0;   // 16B-aligned
    }

    float4v acc[NT_];
#pragma unroll
    for (int i = 0; i < NT_; ++i) acc[i] = (float4v)(0.0f);

#pragma unroll
    for (int ks = 0; ks < KSTEPS; ++ks) {
        const short8 a = *(const short8*)&xs[sidx[ks]];
        short8 br[NT_];
#pragma unroll
        for (int nt = 0; nt < NT_; ++nt)
            br[nt] = wfl[(ks * NT_ + nt) * 64 + lane];
#pragma unroll
        for (int nt = 0; nt < NT_; ++nt)
            acc[nt] = __builtin_amdgcn_mfma_f32_16x16x32_bf16(a, br[nt], acc[nt], 0, 0, 0);
    }

    __syncthreads();   // all waves done reading xs/wfl before ys overwrites

    // Epilogue: transpose via LDS, coalesced float4 stores.
    // D layout: row m = wv*16 + kgrp*4 + j, col = lane&15.
    const int m0 = wv * 16 + kgrp * 4;
    const int cS   = tid / 28;            // store-phase mapping
    const int remS = tid % 28;
    const int hlS  = remS / 7;
    const int fS   = remS % 7;
    int hd = h0 + hlS + 1; if (hd >= H_) hd -= H_;   // roll(+1)

#pragma unroll
    for (int nt = 0; nt < NT_; ++nt) {
        if (nt) __syncthreads();
        float* ys = (nt & 1) ? ys1 : ys0;
        *(float2*)&ys[cgrp * YSLD + m0]     = make_float2(acc[nt][0], acc[nt][1]);
        *(float2*)&ys[cgrp * YSLD + m0 + 2] = make_float2(acc[nt][2], acc[nt][3]);
        __syncthreads();
        const float2 u0 = *(const float2*)&ys[cS * YSLD + hlS * 28 + 4 * fS];
        const float2 u1 = *(const float2*)&ys[cS * YSLD + hlS * 28 + 4 * fS + 2];
        float4 v; v.x = u0.x; v.y = u0.y; v.z = u1.x; v.w = u1.y;
        *(float4*)&out[(((size_t)b * 192 + g * COUT_ + nt * 16 + cS) * H_ + hd) * W_ + 4 * fS] = v;
    }
}

extern "C" void kernel_launch(void* const* d_in, const int* in_sizes, int n_in,
                              void* d_out, int out_size, void* d_ws, size_t ws_size,
                              hipStream_t stream) {
    const float* x = (const float*)d_in[0];
    const float* w = (const float*)d_in[1];
    float* out = (float*)d_out;
    short8* wf = (short8*)d_ws;           // 36*64*16B = 36864 B

    wfrag_kernel<<<36, 64, 0, stream>>>(w, wf);
    conv_mfma_kernel<<<B_ * 7 * 2, 448, 0, stream>>>(x, (const float4*)wf, out);
}